// Round 5
// baseline (3292.694 us; speedup 1.0000x reference)
//
#include <hip/hip_runtime.h>

// Dims (fixed by the problem)
#define S_LEN 512
#define BATCH 256
#define EMB_D 300
#define EMB_PAD 320
#define HID 128
#define SB (S_LEN*BATCH)   // 131072 rows (time-major m = s*B + b)

typedef __attribute__((ext_vector_type(8))) short bf16x8;   // 8 bf16 = 4 VGPRs
typedef __attribute__((ext_vector_type(4))) float f32x4;
typedef unsigned short u16;
typedef unsigned int   u32;

// ---- bf16 <-> f32 helpers ----
__device__ __forceinline__ float b2f(u16 u) {
    union { u32 i; float f; } v; v.i = ((u32)u) << 16; return v.f;
}
__device__ __forceinline__ u16 f2b(float f) {
    union { float f; u32 i; } v; v.f = f;
    u32 r = v.i + 0x7fffu + ((v.i >> 16) & 1u);   // round-to-nearest-even
    return (u16)(r >> 16);
}
__device__ __forceinline__ float sigf(float x) {
    return __builtin_amdgcn_rcpf(1.f + __expf(-x));
}
__device__ __forceinline__ float tanhf_fast(float x) {
    float e = __expf(2.f * x);
    return 1.f - 2.f * __builtin_amdgcn_rcpf(e + 1.f);
}

// ---- dtype detector: flag=1 if float tensors are bf16, 0 if f32 ----
__global__ void k_detect(const u16* __restrict__ emb_u, int* __restrict__ flag) {
    __shared__ int cnt;
    if (threadIdx.x == 0) cnt = 0;
    __syncthreads();
    float v = b2f(emb_u[2 * threadIdx.x + 64]);
    float a = fabsf(v);
    if (a > 1e-4f && a < 16.f) atomicAdd(&cnt, 1);
    __syncthreads();
    if (threadIdx.x == 0) *flag = (cnt > 128) ? 1 : 0;
}

// ---- weight packing: gate-row permutation row' = 4*j + t (t: 0=i,1=f,2=g,3=o) ----
__global__ void k_packw(const void* __restrict__ src, u16* __restrict__ dst,
                        int Kin, int Kpad, int total, const int* __restrict__ flag) {
    int i = blockIdx.x * 256 + threadIdx.x;
    if (i >= total) return;
    int n = i / Kpad, k = i - n * Kpad;
    int d = n >> 9, r = n & 511, j = r >> 2, t = r & 3;
    size_t si = (size_t)((d << 9) + (t << 7) + j) * Kin + k;
    u16 v = 0;
    if (k < Kin) {
        if (*flag) v = ((const u16*)src)[si];
        else       v = f2b(((const float*)src)[si]);
    }
    dst[i] = v;
}

__global__ void k_packb(const void* __restrict__ src, float* __restrict__ dst,
                        const int* __restrict__ flag) {
    int i = blockIdx.x * 256 + threadIdx.x;
    if (i >= 1024) return;
    int d = i >> 9, r = i & 511, j = r >> 2, t = r & 3;
    size_t si = (d << 9) + (t << 7) + j;
    dst[i] = (*flag) ? b2f(((const u16*)src)[si]) : ((const float*)src)[si];
}

// ---- one-time embedding gather: Apack[m][320] bf16, zero-padded 300->320.
// Moves the scattered gather + f32->bf16 conversion OUT of the GEMM inner loop.
__global__ __launch_bounds__(256) void k_embA(const int* __restrict__ tok,
                                              const void* __restrict__ emb,
                                              u16* __restrict__ Ap,
                                              const int* __restrict__ flag) {
    int idx = blockIdx.x * 256 + threadIdx.x;       // one thread per 8 cols
    if (idx >= SB * 40) return;
    int m = idx / 40, c8 = (idx - m * 40) * 8;
    int s = m >> 8, b = m & 255;
    size_t row = (size_t)tok[b * S_LEN + s];
    ushort4 lo, hi;
    lo.x = lo.y = lo.z = lo.w = 0;
    hi.x = hi.y = hi.z = hi.w = 0;
    if (*flag) {                                     // bf16 source (rows 8B-aligned)
        const u16* p = (const u16*)emb + row * EMB_D + c8;
        if (c8 + 8 <= EMB_D) { lo = *(const ushort4*)p; hi = *(const ushort4*)(p + 4); }
        else if (c8 < EMB_D) { lo = *(const ushort4*)p; }          // c8==296: cols 296-299
    } else {                                         // f32 source (rows 16B-aligned)
        const float* p = (const float*)emb + row * EMB_D + c8;
        if (c8 + 8 <= EMB_D) {
            float4 f0 = *(const float4*)p, f1 = *(const float4*)(p + 4);
            lo.x = f2b(f0.x); lo.y = f2b(f0.y); lo.z = f2b(f0.z); lo.w = f2b(f0.w);
            hi.x = f2b(f1.x); hi.y = f2b(f1.y); hi.z = f2b(f1.z); hi.w = f2b(f1.w);
        } else if (c8 < EMB_D) {
            float4 f0 = *(const float4*)p;
            lo.x = f2b(f0.x); lo.y = f2b(f0.y); lo.z = f2b(f0.z); lo.w = f2b(f0.w);
        }
    }
    *(ushort4*)(Ap + (size_t)m * EMB_PAD + c8)     = lo;
    *(ushort4*)(Ap + (size_t)m * EMB_PAD + c8 + 4) = hi;
}

// ---- dense projection GEMM, register-direct: NO LDS, NO barriers.
// MFMA fragments are 16B-contiguous rows -> load straight global->VGPR.
// Block = 8 waves (2m x 4n of 32x32 wave-tiles) = 64m x 128n. 2-deep pipeline.
// A rows bf16 [*, KPAD] (Apack or h0seq); W packed rows [N, KPAD] (L2-hot).
// Grid: x = M/64 (fastest -> consecutive blocks share the B-strip), y = N/128.
// C written bf16 at (n>>9)*SB*512 + m*512 + (n&511).
template<int KPAD>
__global__ __launch_bounds__(512) void k_gemm(const u16* __restrict__ A,
                                              const u16* __restrict__ W,
                                              const float* __restrict__ bias,
                                              u16* __restrict__ C) {
    const int tid  = threadIdx.x;
    const int m0   = blockIdx.x * 64;
    const int n0   = blockIdx.y * 128;
    const int w    = tid >> 6, lane = tid & 63, quad = lane >> 4, l16 = lane & 15;
    const int mq   = (w >> 2) * 32, nq = (w & 3) * 32;

    const u16* pa = A + (size_t)(m0 + mq + l16) * KPAD + quad * 8;   // mt=0 row
    const u16* pb = W + (size_t)(n0 + nq + l16) * KPAD + quad * 8;   // nt=0 row

    f32x4 acc[2][2] = {};
    constexpr int KS = KPAD / 32;
    bf16x8 ca0 = *(const bf16x8*)(pa);
    bf16x8 ca1 = *(const bf16x8*)(pa + (size_t)16 * KPAD);
    bf16x8 cb0 = *(const bf16x8*)(pb);
    bf16x8 cb1 = *(const bf16x8*)(pb + (size_t)16 * KPAD);
#pragma unroll
    for (int kk = 0; kk < KS; ++kk) {
        bf16x8 na0, na1, nb0, nb1;
        if (kk + 1 < KS) {                           // prefetch next K-slice
            na0 = *(const bf16x8*)(pa + (kk + 1) * 32);
            na1 = *(const bf16x8*)(pa + (size_t)16 * KPAD + (kk + 1) * 32);
            nb0 = *(const bf16x8*)(pb + (kk + 1) * 32);
            nb1 = *(const bf16x8*)(pb + (size_t)16 * KPAD + (kk + 1) * 32);
        }
        acc[0][0] = __builtin_amdgcn_mfma_f32_16x16x32_bf16(ca0, cb0, acc[0][0], 0, 0, 0);
        acc[0][1] = __builtin_amdgcn_mfma_f32_16x16x32_bf16(ca0, cb1, acc[0][1], 0, 0, 0);
        acc[1][0] = __builtin_amdgcn_mfma_f32_16x16x32_bf16(ca1, cb0, acc[1][0], 0, 0, 0);
        acc[1][1] = __builtin_amdgcn_mfma_f32_16x16x32_bf16(ca1, cb1, acc[1][1], 0, 0, 0);
        if (kk + 1 < KS) { ca0 = na0; ca1 = na1; cb0 = nb0; cb1 = nb1; }
    }
    // C/D layout: col = lane&15, row = quad*4 + reg  [m89-verified]
#pragma unroll
    for (int mt = 0; mt < 2; ++mt)
#pragma unroll
        for (int nt = 0; nt < 2; ++nt)
#pragma unroll
            for (int r = 0; r < 4; ++r) {
                int m = m0 + mq + mt * 16 + quad * 4 + r;
                int n = n0 + nq + nt * 16 + l16;
                float v = acc[mt][nt][r] + bias[n];
                int dd = n >> 9, nn = n & 511;
                C[(size_t)dd * SB * 512 + (size_t)m * 512 + nn] = f2b(v);
            }
}

// ---- tier-C fallback (ws too small for Apack): round-3 gather GEMM, EMBED only.
__global__ __launch_bounds__(256) void k_gemm_gather(const int* __restrict__ tok,
                                                     const void* __restrict__ Asrc,
                                                     const u16* __restrict__ W,
                                                     const float* __restrict__ bias,
                                                     u16* __restrict__ C,
                                                     const int* __restrict__ flag) {
    const int KPAD = 320;
    __shared__ __align__(16) u16 As[64 * 40];
    __shared__ __align__(16) u16 Bs[64 * 40];
    const int tid  = threadIdx.x;
    const int m0   = blockIdx.x * 64;
    const int n0   = blockIdx.y * 64;
    const int w    = tid >> 6, lane = tid & 63, quad = lane >> 4, l16 = lane & 15;
    const int mq   = (w >> 1) * 32, nq = (w & 1) * 32;
    const int row  = tid >> 2, seg = tid & 3;

    int m = m0 + row, s = m >> 8, b = m & 255;
    bool is_bf = (*flag != 0);
    size_t arow_off = (size_t)tok[b * S_LEN + s] * EMB_D;
    const u16* brow = W + (size_t)(n0 + row) * KPAD;

    f32x4 acc[2][2] = {};
#pragma unroll
    for (int kk = 0; kk < KPAD / 32; ++kk) {
        uint4 va, vb;
        u32 u[4];
        if (is_bf) {
            const u16* ar = (const u16*)Asrc + arow_off;
#pragma unroll
            for (int i = 0; i < 4; ++i) {
                int c = kk * 32 + seg * 8 + 2 * i;
                u[i] = (c < EMB_D) ? *(const u32*)(ar + c) : 0u;
            }
        } else {
            const float* ar = (const float*)Asrc + arow_off;
#pragma unroll
            for (int i = 0; i < 4; ++i) {
                int c = kk * 32 + seg * 8 + 2 * i;
                if (c < EMB_D) {
                    float2 f = *(const float2*)(ar + c);
                    u[i] = (u32)f2b(f.x) | ((u32)f2b(f.y) << 16);
                } else u[i] = 0u;
            }
        }
        va.x = u[0]; va.y = u[1]; va.z = u[2]; va.w = u[3];
        vb = *((const uint4*)brow + kk * 4 + seg);
        __syncthreads();
        *(uint4*)(As + row * 40 + seg * 8) = va;
        *(uint4*)(Bs + row * 40 + seg * 8) = vb;
        __syncthreads();
        bf16x8 af[2], bfr[2];
#pragma unroll
        for (int mt = 0; mt < 2; ++mt)
            af[mt] = *(const bf16x8*)(As + (mq + mt * 16 + l16) * 40 + quad * 8);
#pragma unroll
        for (int nt = 0; nt < 2; ++nt)
            bfr[nt] = *(const bf16x8*)(Bs + (nq + nt * 16 + l16) * 40 + quad * 8);
#pragma unroll
        for (int mt = 0; mt < 2; ++mt)
#pragma unroll
            for (int nt = 0; nt < 2; ++nt)
                acc[mt][nt] = __builtin_amdgcn_mfma_f32_16x16x32_bf16(af[mt], bfr[nt], acc[mt][nt], 0, 0, 0);
    }
#pragma unroll
    for (int mt = 0; mt < 2; ++mt)
#pragma unroll
        for (int nt = 0; nt < 2; ++nt)
#pragma unroll
            for (int r = 0; r < 4; ++r) {
                int mm = m0 + mq + mt * 16 + quad * 4 + r;
                int n  = n0 + nq + nt * 16 + l16;
                float v = acc[mt][nt][r] + bias[n];
                int dd = n >> 9, nn = n & 511;
                C[(size_t)dd * SB * 512 + (size_t)mm * 512 + nn] = f2b(v);
            }
}

// ---- LSTM recurrence. Block = (dir, 16-batch group); 1024 thr = 16 waves.
// [r2: DMA staging -35%; r1 vm-drain null; r3 occupancy null -> lockstep-
// barrier-bound; parked at ~570us]
template<bool IS_L0>
__global__ __launch_bounds__(1024) void k_lstm(const u16* __restrict__ gx, size_t gx_stride,
                                               const u16* __restrict__ Whp, int dir0,
                                               u16* __restrict__ h0seq, float* __restrict__ hT) {
    const int tid  = threadIdx.x;
    const int dl   = blockIdx.x >> 4;
    const int d    = dir0 + dl;
    const int bg   = blockIdx.x & 15;
    const int wv   = tid >> 6, lane = tid & 63, quad = lane >> 4, col = lane & 15;

    __shared__ __align__(16) u16 hbuf[2][16][136];   // [buf][b-local][h j], padded
    __shared__ __align__(16) u16 gxb [2][16][520];   // [buf][b-local][512 gates], padded

    for (int i = tid; i < 2 * 16 * 136; i += 1024) ((u16*)hbuf)[i] = 0;

    // A-frags of W_hh: A[m=lane&15][k=quad*8+j]  [m120-verified]
    const u16* Wd = Whp + (size_t)d * 512 * 128;
    bf16x8 wf[2][4];
#pragma unroll
    for (int mt = 0; mt < 2; ++mt)
#pragma unroll
        for (int ks = 0; ks < 4; ++ks)
            wf[mt][ks] = *(const bf16x8*)(Wd + (size_t)(((wv * 2 + mt) * 16) + col) * 128 + ks * 32 + quad * 8);

    const u16* gxd = gx + (size_t)dl * gx_stride;
    auto sidx = [&](int si) { return (d == 0) ? si : (S_LEN - 1 - si); };

    // wave wv DMAs one dense 1KB gx row (batch-local row wv) per step
    auto prefetch = [&](int s, int P) {
        const u16* g0 = gxd + ((size_t)s * BATCH + bg * 16 + wv) * 512 + lane * 8;
        __builtin_amdgcn_global_load_lds((const __attribute__((address_space(1))) void*)g0,
            (__attribute__((address_space(3))) void*)&gxb[P][wv][0], 16, 0, 0);
    };

    float c[2] = {0.f, 0.f};

    auto step = [&](int si, int P) {            // P = si & 1 (literal at call sites)
        if (si + 1 < S_LEN) prefetch(sidx(si + 1), P ^ 1);
        if constexpr (IS_L0) {
            if (si > 0) {                        // store PREV step's h (published by barrier)
                int sp = sidx(si - 1);
                ushort2 hv = *(const ushort2*)&hbuf[P][wv][lane * 2];
                *(ushort2*)(h0seq + ((size_t)sp * BATCH + bg * 16 + wv) * 256 + (d << 7) + lane * 2) = hv;
            }
        }
        bf16x8 hf[4];
#pragma unroll
        for (int ks = 0; ks < 4; ++ks)
            hf[ks] = *(const bf16x8*)&hbuf[P][col][ks * 32 + quad * 8];
        f32x4 z[2];
#pragma unroll
        for (int mt = 0; mt < 2; ++mt) {
            ushort4 gv = *(const ushort4*)&gxb[P][col][(wv * 2 + mt) * 16 + quad * 4];
            z[mt][0] = b2f(gv.x); z[mt][1] = b2f(gv.y); z[mt][2] = b2f(gv.z); z[mt][3] = b2f(gv.w);
        }
#pragma unroll
        for (int ks = 0; ks < 4; ++ks)
#pragma unroll
            for (int mt = 0; mt < 2; ++mt)
                z[mt] = __builtin_amdgcn_mfma_f32_16x16x32_bf16(wf[mt][ks], hf[ks], z[mt], 0, 0, 0);
#pragma unroll
        for (int mt = 0; mt < 2; ++mt) {
            float iv = sigf(z[mt][0]), fv = sigf(z[mt][1]);
            float gg = tanhf_fast(z[mt][2]), ov = sigf(z[mt][3]);
            c[mt] = fv * c[mt] + iv * gg;
            float hv = ov * tanhf_fast(c[mt]);
            const int j = (wv * 2 + mt) * 4 + quad;          // hidden-unit index
            hbuf[P ^ 1][col][j] = f2b(hv);
            if constexpr (!IS_L0) {
                if (si == S_LEN - 1)
                    hT[((size_t)d * BATCH + bg * 16 + col) * 128 + j] = hv;
            }
        }
        __syncthreads();
    };

    prefetch(sidx(0), 0);
    __syncthreads();                            // hbuf zeros + gx(s0) visible

    for (int si = 0; si < S_LEN; si += 2) {
        step(si, 0);
        step(si + 1, 1);
    }

    if constexpr (IS_L0) {                      // final step's h (in hbuf[0])
        int sp = sidx(S_LEN - 1);
        ushort2 hv = *(const ushort2*)&hbuf[0][wv][lane * 2];
        *(ushort2*)(h0seq + ((size_t)sp * BATCH + bg * 16 + wv) * 256 + (d << 7) + lane * 2) = hv;
    }
}

// ---- FC head (dtype-flagged weights and output) ----
__global__ void k_fc(const float* __restrict__ hT,
                     const void* __restrict__ fc1w, const void* __restrict__ fc1b,
                     const void* __restrict__ fc2w, const void* __restrict__ fc2b,
                     void* __restrict__ out, const int* __restrict__ flag) {
    int b = blockIdx.x, j = threadIdx.x;
    bool is_bf = (*flag != 0);
    __shared__ float u[128];
    float a = is_bf ? b2f(((const u16*)fc1b)[j]) : ((const float*)fc1b)[j];
    for (int k = 0; k < 256; ++k) {
        float x = hT[((size_t)(k >> 7) * BATCH + b) * 128 + (k & 127)];
        float w = is_bf ? b2f(((const u16*)fc1w)[j * 256 + k]) : ((const float*)fc1w)[j * 256 + k];
        a += x * w;
    }
    u[j] = fmaxf(a, 0.f);
    __syncthreads();
    if (j < 2) {
        float a2 = is_bf ? b2f(((const u16*)fc2b)[j]) : ((const float*)fc2b)[j];
        for (int q = 0; q < 128; ++q) {
            float w = is_bf ? b2f(((const u16*)fc2w)[j * 128 + q]) : ((const float*)fc2w)[j * 128 + q];
            a2 += u[q] * w;
        }
        if (is_bf) ((u16*)out)[b * 2 + j] = f2b(a2);
        else       ((float*)out)[b * 2 + j] = a2;
    }
}

extern "C" void kernel_launch(void* const* d_in, const int* in_sizes, int n_in,
                              void* d_out, int out_size, void* d_ws, size_t ws_size,
                              hipStream_t stream) {
    const int*  tok   = (const int*)d_in[0];
    const void* emb   = d_in[1];
    const void* w_ih0 = d_in[2];
    const void* w_hh0 = d_in[3];
    const void* b0    = d_in[4];
    const void* w_ih1 = d_in[5];
    const void* w_hh1 = d_in[6];
    const void* b1    = d_in[7];
    const void* fc1w  = d_in[8];
    const void* fc1b  = d_in[9];
    const void* fc2w  = d_in[10];
    const void* fc2b  = d_in[11];

    char* ws = (char*)d_ws;
    size_t off = 0;
    auto alloc = [&](size_t bytes) -> void* {
        void* p = ws + off; off += (bytes + 255) & ~(size_t)255; return p;
    };
    int*   flag  = (int*)alloc(256);
    u16*   Wp0   = (u16*)alloc(1024 * 320 * 2);
    u16*   Wp1   = (u16*)alloc(1024 * 256 * 2);
    u16*   Whp0  = (u16*)alloc(1024 * 128 * 2);
    u16*   Whp1  = (u16*)alloc(1024 * 128 * 2);
    float* bp0   = (float*)alloc(1024 * 4);
    float* bp1   = (float*)alloc(1024 * 4);
    float* hT    = (float*)alloc((size_t)2 * BATCH * 128 * 4);
    u16*   h0seq = (u16*)alloc((size_t)SB * 256 * 2);            // 64 MiB
    size_t apack_b = (size_t)SB * EMB_PAD * 2;                   // 84 MiB
    size_t gx1     = (size_t)SB * 512 * 2;                       // one dir: 128 MiB
    bool big = ws_size >= off + apack_b + 2 * gx1 + 1024;        // Apack + both dirs
    bool mid = ws_size >= off + apack_b + gx1 + 1024;            // Apack + one dir
    u16* Apack = nullptr;
    u16* gx;
    if (mid) { Apack = (u16*)alloc(apack_b); gx = (u16*)alloc(big ? 2 * gx1 : gx1); }
    else     { gx = (u16*)alloc(gx1); }                          // tier C: gather GEMM

    k_detect<<<1, 256, 0, stream>>>((const u16*)emb, flag);

    k_packw<<<(1024 * 320 + 255) / 256, 256, 0, stream>>>(w_ih0, Wp0, 300, 320, 1024 * 320, flag);
    k_packw<<<(1024 * 256 + 255) / 256, 256, 0, stream>>>(w_ih1, Wp1, 256, 256, 1024 * 256, flag);
    k_packw<<<(1024 * 128 + 255) / 256, 256, 0, stream>>>(w_hh0, Whp0, 128, 128, 1024 * 128, flag);
    k_packw<<<(1024 * 128 + 255) / 256, 256, 0, stream>>>(w_hh1, Whp1, 128, 128, 1024 * 128, flag);
    k_packb<<<4, 256, 0, stream>>>(b0, bp0, flag);
    k_packb<<<4, 256, 0, stream>>>(b1, bp1, flag);

    if (Apack)
        k_embA<<<(SB * 40 + 255) / 256, 256, 0, stream>>>(tok, emb, Apack, flag);

    if (big) {
        k_gemm<320><<<dim3(SB / 64, 1024 / 128), 512, 0, stream>>>(Apack, Wp0, bp0, gx);
        k_lstm<true ><<<32, 1024, 0, stream>>>(gx, (size_t)SB * 512, Whp0, 0, h0seq, nullptr);
        k_gemm<256><<<dim3(SB / 64, 1024 / 128), 512, 0, stream>>>(h0seq, Wp1, bp1, gx);
        k_lstm<false><<<32, 1024, 0, stream>>>(gx, (size_t)SB * 512, Whp1, 0, nullptr, hT);
    } else {
        for (int d = 0; d < 2; ++d) {
            if (Apack)
                k_gemm<320><<<dim3(SB / 64, 512 / 128), 512, 0, stream>>>(
                    Apack, Wp0 + (size_t)d * 512 * 320, bp0 + d * 512, gx);
            else
                k_gemm_gather<<<dim3(SB / 64, 512 / 64), 256, 0, stream>>>(
                    tok, emb, Wp0 + (size_t)d * 512 * 320, bp0 + d * 512, gx, flag);
            k_lstm<true ><<<16, 1024, 0, stream>>>(gx, 0, Whp0, d, h0seq, nullptr);
        }
        for (int d = 0; d < 2; ++d) {
            k_gemm<256><<<dim3(SB / 64, 512 / 128), 512, 0, stream>>>(
                h0seq, Wp1 + (size_t)d * 512 * 256, bp1 + d * 512, gx);
            k_lstm<false><<<16, 1024, 0, stream>>>(gx, 0, Whp1, d, nullptr, hT);
        }
    }
    k_fc<<<256, 128, 0, stream>>>(hT, fc1w, fc1b, fc2w, fc2b, d_out, flag);
}

// Round 6
// 1802.926 us; speedup vs baseline: 1.8263x; 1.8263x over previous
//
#include <hip/hip_runtime.h>

// Dims (fixed by the problem)
#define S_LEN 512
#define BATCH 256
#define EMB_D 300
#define EMB_PAD 320
#define HID 128
#define SB (S_LEN*BATCH)   // 131072 rows (time-major m = s*B + b)
#define CH 128             // time-chunk length
#define NCH 4              // number of chunks

typedef __attribute__((ext_vector_type(8))) short bf16x8;   // 8 bf16 = 4 VGPRs
typedef __attribute__((ext_vector_type(4))) float f32x4;
typedef unsigned short u16;
typedef unsigned int   u32;

// ---- bf16 <-> f32 helpers ----
__device__ __forceinline__ float b2f(u16 u) {
    union { u32 i; float f; } v; v.i = ((u32)u) << 16; return v.f;
}
__device__ __forceinline__ u16 f2b(float f) {
    union { float f; u32 i; } v; v.f = f;
    u32 r = v.i + 0x7fffu + ((v.i >> 16) & 1u);   // round-to-nearest-even
    return (u16)(r >> 16);
}
__device__ __forceinline__ float sigf(float x) {
    return __builtin_amdgcn_rcpf(1.f + __expf(-x));
}
__device__ __forceinline__ float tanhf_fast(float x) {
    float e = __expf(2.f * x);
    return 1.f - 2.f * __builtin_amdgcn_rcpf(e + 1.f);
}

// ---- dtype detector: flag=1 if float tensors are bf16, 0 if f32 ----
__global__ void k_detect(const u16* __restrict__ emb_u, int* __restrict__ flag) {
    __shared__ int cnt;
    if (threadIdx.x == 0) cnt = 0;
    __syncthreads();
    float v = b2f(emb_u[2 * threadIdx.x + 64]);
    float a = fabsf(v);
    if (a > 1e-4f && a < 16.f) atomicAdd(&cnt, 1);
    __syncthreads();
    if (threadIdx.x == 0) *flag = (cnt > 128) ? 1 : 0;
}

// ---- weight packing: gate-row permutation row' = 4*j + t (t: 0=i,1=f,2=g,3=o) ----
__global__ void k_packw(const void* __restrict__ src, u16* __restrict__ dst,
                        int Kin, int Kpad, int total, const int* __restrict__ flag) {
    int i = blockIdx.x * 256 + threadIdx.x;
    if (i >= total) return;
    int n = i / Kpad, k = i - n * Kpad;
    int d = n >> 9, r = n & 511, j = r >> 2, t = r & 3;
    size_t si = (size_t)((d << 9) + (t << 7) + j) * Kin + k;
    u16 v = 0;
    if (k < Kin) {
        if (*flag) v = ((const u16*)src)[si];
        else       v = f2b(((const float*)src)[si]);
    }
    dst[i] = v;
}

__global__ void k_packb(const void* __restrict__ src, float* __restrict__ dst,
                        const int* __restrict__ flag) {
    int i = blockIdx.x * 256 + threadIdx.x;
    if (i >= 1024) return;
    int d = i >> 9, r = i & 511, j = r >> 2, t = r & 3;
    size_t si = (d << 9) + (t << 7) + j;
    dst[i] = (*flag) ? b2f(((const u16*)src)[si]) : ((const float*)src)[si];
}

// ---- chunked projection GEMM (r3-proven 64x64 structure).
// Computes gx for ONE time-chunk, BOTH directions. Grid: x = chunk M-tiles
// (32768/64 = 512), y = 16 n-tiles (0-7 dir0, 8-15 dir1). Each dir's m-rows
// start at its own chunk base (dir0 ascending chunks, dir1 descending).
// C (gxc) layout: [dir][sc][b][512], sc = chunk-local step.
template<int KPAD, bool EMBED>
__global__ __launch_bounds__(256) void k_gemm(const int* __restrict__ tok,
                                              const void* __restrict__ Asrc,
                                              const u16* __restrict__ W,
                                              const float* __restrict__ bias,
                                              u16* __restrict__ C,
                                              const int* __restrict__ flag,
                                              int soff0, int soff1) {
    __shared__ __align__(16) u16 As[64 * 40];   // K-slice 32 padded to 40
    __shared__ __align__(16) u16 Bs[64 * 40];
    const int tid  = threadIdx.x;
    const int by   = blockIdx.y;
    const int dir  = by >> 3;
    const int n0   = (by & 7) * 64;              // within dir's 512 cols
    const int m0   = blockIdx.x * 64;            // within chunk (0..32767)
    const int soff = dir ? soff1 : soff0;
    const size_t mg0 = (size_t)soff * BATCH;     // global row base for this dir-chunk
    const int w    = tid >> 6, lane = tid & 63, quad = lane >> 4, l16 = lane & 15;
    const int mq   = (w >> 1) * 32, nq = (w & 1) * 32;
    const int row  = tid >> 2, seg = tid & 3;

    bool is_bf = true;
    size_t arow_off = 0;
    if constexpr (EMBED) {
        size_t m = mg0 + m0 + row;
        int s = (int)(m >> 8), b = (int)(m & 255);
        is_bf = (*flag != 0);
        arow_off = (size_t)tok[b * S_LEN + s] * EMB_D;
    } else {
        arow_off = (mg0 + m0 + row) * KPAD;
    }
    const u16* brow = W + (size_t)(dir * 512 + n0 + row) * KPAD;

    f32x4 acc[2][2] = {};
    const int KSTEPS = KPAD / 32;
#pragma unroll
    for (int kk = 0; kk < KSTEPS; ++kk) {
        uint4 va, vb;
        if constexpr (EMBED) {
            u32 u[4];
            if (is_bf) {
                const u16* ar = (const u16*)Asrc + arow_off;
#pragma unroll
                for (int i = 0; i < 4; ++i) {
                    int c = kk * 32 + seg * 8 + 2 * i;       // even -> 4B aligned pair
                    u[i] = (c < EMB_D) ? *(const u32*)(ar + c) : 0u;
                }
            } else {
                const float* ar = (const float*)Asrc + arow_off;
#pragma unroll
                for (int i = 0; i < 4; ++i) {
                    int c = kk * 32 + seg * 8 + 2 * i;
                    if (c < EMB_D) {
                        float2 f = *(const float2*)(ar + c);
                        u[i] = (u32)f2b(f.x) | ((u32)f2b(f.y) << 16);
                    } else u[i] = 0u;
                }
            }
            va.x = u[0]; va.y = u[1]; va.z = u[2]; va.w = u[3];
        } else {
            va = *((const uint4*)((const u16*)Asrc + arow_off) + kk * 4 + seg);
        }
        vb = *((const uint4*)brow + kk * 4 + seg);
        __syncthreads();
        *(uint4*)(As + row * 40 + seg * 8) = va;
        *(uint4*)(Bs + row * 40 + seg * 8) = vb;
        __syncthreads();
        bf16x8 af[2], bfr[2];
#pragma unroll
        for (int mt = 0; mt < 2; ++mt)
            af[mt] = *(const bf16x8*)(As + (mq + mt * 16 + l16) * 40 + quad * 8);
#pragma unroll
        for (int nt = 0; nt < 2; ++nt)
            bfr[nt] = *(const bf16x8*)(Bs + (nq + nt * 16 + l16) * 40 + quad * 8);
#pragma unroll
        for (int mt = 0; mt < 2; ++mt)
#pragma unroll
            for (int nt = 0; nt < 2; ++nt)
                acc[mt][nt] = __builtin_amdgcn_mfma_f32_16x16x32_bf16(af[mt], bfr[nt], acc[mt][nt], 0, 0, 0);
    }
    // C/D layout: col = lane&15, row = quad*4 + reg  [m89-verified]
#pragma unroll
    for (int mt = 0; mt < 2; ++mt)
#pragma unroll
        for (int nt = 0; nt < 2; ++nt)
#pragma unroll
            for (int r = 0; r < 4; ++r) {
                int mloc = m0 + mq + mt * 16 + quad * 4 + r;     // within chunk
                int nloc = n0 + nq + nt * 16 + l16;              // within dir
                float v = acc[mt][nt][r] + bias[dir * 512 + nloc];
                C[(size_t)dir * CH * BATCH * 512 + (size_t)mloc * 512 + nloc] = f2b(v);
            }
}

// ---- LSTM recurrence, one time-chunk, BOTH directions (32 blocks).
// Block = (dir = blockIdx>>4, 16-batch group); 1024 thr = 16 waves. Wave wv
// owns gate tiles wv*2, wv*2+1. Internals = r3-proven (DMA-staged gx rows,
// double-buffered LDS, dense h0seq stores). h/c state carried across chunk
// dispatches via hstate/cstate (k==0 initializes to zero in-kernel).
template<bool IS_L0>
__global__ __launch_bounds__(1024) void k_lstm(const u16* __restrict__ gxc,
                                               const u16* __restrict__ Whp,
                                               u16* __restrict__ h0seq, float* __restrict__ hT,
                                               u16* __restrict__ hstate, float* __restrict__ cstate,
                                               int k) {
    const int tid  = threadIdx.x;
    const int d    = blockIdx.x >> 4;
    const int bg   = blockIdx.x & 15;
    const int wv   = tid >> 6, lane = tid & 63, quad = lane >> 4, col = lane & 15;
    const int soff = (d == 0) ? CH * k : CH * (NCH - 1 - k);

    __shared__ __align__(16) u16 hbuf[2][16][136];   // [buf][b-local][h j], padded
    __shared__ __align__(16) u16 gxb [2][16][520];   // [buf][b-local][512 gates], padded

    for (int i = tid; i < 2 * 16 * 136; i += 1024) ((u16*)hbuf)[i] = 0;
    __syncthreads();                                  // zero visible before state load
    if (k > 0) {
        for (int i = tid; i < 16 * 128; i += 1024) {
            int bl = i >> 7, j = i & 127;
            hbuf[0][bl][j] = hstate[((size_t)d * BATCH + bg * 16 + bl) * 128 + j];
        }
    }

    // A-frags of W_hh: A[m=lane&15][k=quad*8+j]  [m120-verified]
    const u16* Wd = Whp + (size_t)d * 512 * 128;
    bf16x8 wf[2][4];
#pragma unroll
    for (int mt = 0; mt < 2; ++mt)
#pragma unroll
        for (int ks = 0; ks < 4; ++ks)
            wf[mt][ks] = *(const bf16x8*)(Wd + (size_t)(((wv * 2 + mt) * 16) + col) * 128 + ks * 32 + quad * 8);

    const u16* gxd = gxc + (size_t)d * CH * BATCH * 512;
    auto sloc = [&](int si) { return (d == 0) ? si : (CH - 1 - si); };   // chunk-local row

    // wave wv DMAs one dense 1KB gx row (batch-local row wv) per step
    auto prefetch = [&](int si, int P) {
        const u16* g0 = gxd + ((size_t)sloc(si) * BATCH + bg * 16 + wv) * 512 + lane * 8;
        __builtin_amdgcn_global_load_lds((const __attribute__((address_space(1))) void*)g0,
            (__attribute__((address_space(3))) void*)&gxb[P][wv][0], 16, 0, 0);
    };

    float c[2];
#pragma unroll
    for (int mt = 0; mt < 2; ++mt)
        c[mt] = (k > 0) ? cstate[((size_t)d * BATCH + bg * 16 + col) * 128 + (wv * 2 + mt) * 4 + quad] : 0.f;

    auto step = [&](int si, int P) {            // P = si & 1 (literal at call sites)
        if (si + 1 < CH) prefetch(si + 1, P ^ 1);
        if constexpr (IS_L0) {
            if (si > 0) {                        // store PREV step's h (published by barrier)
                int sp = soff + ((d == 0) ? (si - 1) : (CH - si));
                ushort2 hv = *(const ushort2*)&hbuf[P][wv][lane * 2];
                *(ushort2*)(h0seq + ((size_t)sp * BATCH + bg * 16 + wv) * 256 + (d << 7) + lane * 2) = hv;
            }
        }
        bf16x8 hf[4];
#pragma unroll
        for (int ks = 0; ks < 4; ++ks)
            hf[ks] = *(const bf16x8*)&hbuf[P][col][ks * 32 + quad * 8];
        f32x4 z[2];
#pragma unroll
        for (int mt = 0; mt < 2; ++mt) {
            ushort4 gv = *(const ushort4*)&gxb[P][col][(wv * 2 + mt) * 16 + quad * 4];
            z[mt][0] = b2f(gv.x); z[mt][1] = b2f(gv.y); z[mt][2] = b2f(gv.z); z[mt][3] = b2f(gv.w);
        }
#pragma unroll
        for (int ks = 0; ks < 4; ++ks)
#pragma unroll
            for (int mt = 0; mt < 2; ++mt)
                z[mt] = __builtin_amdgcn_mfma_f32_16x16x32_bf16(wf[mt][ks], hf[ks], z[mt], 0, 0, 0);
#pragma unroll
        for (int mt = 0; mt < 2; ++mt) {
            float iv = sigf(z[mt][0]), fv = sigf(z[mt][1]);
            float gg = tanhf_fast(z[mt][2]), ov = sigf(z[mt][3]);
            c[mt] = fv * c[mt] + iv * gg;
            float hv = ov * tanhf_fast(c[mt]);
            const int j = (wv * 2 + mt) * 4 + quad;          // hidden-unit index
            hbuf[P ^ 1][col][j] = f2b(hv);
            if constexpr (!IS_L0) {
                if (k == NCH - 1 && si == CH - 1)
                    hT[((size_t)d * BATCH + bg * 16 + col) * 128 + j] = hv;
            }
        }
        __syncthreads();
    };

    prefetch(0, 0);
    __syncthreads();                            // hbuf init + gx(step 0) visible

    for (int si = 0; si < CH; si += 2) {
        step(si, 0);
        step(si + 1, 1);
    }

    if constexpr (IS_L0) {                      // final step's h (in hbuf[0])
        int sp = soff + ((d == 0) ? (CH - 1) : 0);
        ushort2 hv = *(const ushort2*)&hbuf[0][wv][lane * 2];
        *(ushort2*)(h0seq + ((size_t)sp * BATCH + bg * 16 + wv) * 256 + (d << 7) + lane * 2) = hv;
    }
    if (k < NCH - 1) {                          // persist h/c for next chunk
        for (int i = tid; i < 16 * 128; i += 1024) {
            int bl = i >> 7, j = i & 127;
            hstate[((size_t)d * BATCH + bg * 16 + bl) * 128 + j] = hbuf[0][bl][j];
        }
#pragma unroll
        for (int mt = 0; mt < 2; ++mt)
            cstate[((size_t)d * BATCH + bg * 16 + col) * 128 + (wv * 2 + mt) * 4 + quad] = c[mt];
    }
}

// ---- FC head (dtype-flagged weights and output) ----
__global__ void k_fc(const float* __restrict__ hT,
                     const void* __restrict__ fc1w, const void* __restrict__ fc1b,
                     const void* __restrict__ fc2w, const void* __restrict__ fc2b,
                     void* __restrict__ out, const int* __restrict__ flag) {
    int b = blockIdx.x, j = threadIdx.x;
    bool is_bf = (*flag != 0);
    __shared__ float u[128];
    float a = is_bf ? b2f(((const u16*)fc1b)[j]) : ((const float*)fc1b)[j];
    for (int k = 0; k < 256; ++k) {
        float x = hT[((size_t)(k >> 7) * BATCH + b) * 128 + (k & 127)];
        float w = is_bf ? b2f(((const u16*)fc1w)[j * 256 + k]) : ((const float*)fc1w)[j * 256 + k];
        a += x * w;
    }
    u[j] = fmaxf(a, 0.f);
    __syncthreads();
    if (j < 2) {
        float a2 = is_bf ? b2f(((const u16*)fc2b)[j]) : ((const float*)fc2b)[j];
        for (int q = 0; q < 128; ++q) {
            float w = is_bf ? b2f(((const u16*)fc2w)[j * 128 + q]) : ((const float*)fc2w)[j * 128 + q];
            a2 += u[q] * w;
        }
        if (is_bf) ((u16*)out)[b * 2 + j] = f2b(a2);
        else       ((float*)out)[b * 2 + j] = a2;
    }
}

extern "C" void kernel_launch(void* const* d_in, const int* in_sizes, int n_in,
                              void* d_out, int out_size, void* d_ws, size_t ws_size,
                              hipStream_t stream) {
    const int*  tok   = (const int*)d_in[0];
    const void* emb   = d_in[1];
    const void* w_ih0 = d_in[2];
    const void* w_hh0 = d_in[3];
    const void* b0    = d_in[4];
    const void* w_ih1 = d_in[5];
    const void* w_hh1 = d_in[6];
    const void* b1    = d_in[7];
    const void* fc1w  = d_in[8];
    const void* fc1b  = d_in[9];
    const void* fc2w  = d_in[10];
    const void* fc2b  = d_in[11];

    char* ws = (char*)d_ws;
    size_t off = 0;
    auto alloc = [&](size_t bytes) -> void* {
        void* p = ws + off; off += (bytes + 255) & ~(size_t)255; return p;
    };
    int*   flag   = (int*)alloc(256);
    u16*   Wp0    = (u16*)alloc(1024 * 320 * 2);
    u16*   Wp1    = (u16*)alloc(1024 * 256 * 2);
    u16*   Whp0   = (u16*)alloc(1024 * 128 * 2);
    u16*   Whp1   = (u16*)alloc(1024 * 128 * 2);
    float* bp0    = (float*)alloc(1024 * 4);
    float* bp1    = (float*)alloc(1024 * 4);
    float* hT     = (float*)alloc((size_t)2 * BATCH * 128 * 4);
    u16*   hstate = (u16*)alloc((size_t)2 * BATCH * 128 * 2);
    float* cstate = (float*)alloc((size_t)2 * BATCH * 128 * 4);
    u16*   h0seq  = (u16*)alloc((size_t)SB * 256 * 2);               // 64 MiB
    u16*   gxc    = (u16*)alloc((size_t)2 * CH * BATCH * 512 * 2);   // 64 MiB

    k_detect<<<1, 256, 0, stream>>>((const u16*)emb, flag);

    k_packw<<<(1024 * 320 + 255) / 256, 256, 0, stream>>>(w_ih0, Wp0, 300, 320, 1024 * 320, flag);
    k_packw<<<(1024 * 256 + 255) / 256, 256, 0, stream>>>(w_ih1, Wp1, 256, 256, 1024 * 256, flag);
    k_packw<<<(1024 * 128 + 255) / 256, 256, 0, stream>>>(w_hh0, Whp0, 128, 128, 1024 * 128, flag);
    k_packw<<<(1024 * 128 + 255) / 256, 256, 0, stream>>>(w_hh1, Whp1, 128, 128, 1024 * 128, flag);
    k_packb<<<4, 256, 0, stream>>>(b0, bp0, flag);
    k_packb<<<4, 256, 0, stream>>>(b1, bp1, flag);

    const dim3 gg(CH * BATCH / 64, 16);   // (512, 16): x = chunk M-tiles, y = dir*8 + n-tile
    for (int k = 0; k < NCH; ++k) {
        int so0 = CH * k, so1 = CH * (NCH - 1 - k);
        k_gemm<320, true ><<<gg, 256, 0, stream>>>(tok, emb, Wp0, bp0, gxc, flag, so0, so1);
        k_lstm<true ><<<32, 1024, 0, stream>>>(gxc, Whp0, h0seq, nullptr, hstate, cstate, k);
    }
    for (int k = 0; k < NCH; ++k) {
        int so0 = CH * k, so1 = CH * (NCH - 1 - k);
        k_gemm<256, false><<<gg, 256, 0, stream>>>(nullptr, h0seq, Wp1, bp1, gxc, flag, so0, so1);
        k_lstm<false><<<32, 1024, 0, stream>>>(gxc, Whp1, nullptr, hT, hstate, cstate, k);
    }
    k_fc<<<256, 128, 0, stream>>>(hT, fc1w, fc1b, fc2w, fc2b, d_out, flag);
}

// Round 7
// 1560.491 us; speedup vs baseline: 2.1100x; 1.1554x over previous
//
#include <hip/hip_runtime.h>

// Dims (fixed by the problem)
#define S_LEN 512
#define BATCH 256
#define EMB_D 300
#define EMB_PAD 320
#define HID 128
#define SB (S_LEN*BATCH)   // 131072 rows (time-major m = s*B + b)
#define CH 128             // time-chunk length
#define NCH 4              // number of chunks
#define GXC_DIR ((size_t)CH*BATCH*512)   // u16 per dir per buffer
#define SMEM_BYTES 86016   // 84 KiB: 2x84 > 160 KiB -> exactly 1 block/CU (role isolation)

typedef __attribute__((ext_vector_type(8))) short bf16x8;   // 8 bf16 = 4 VGPRs
typedef __attribute__((ext_vector_type(4))) float f32x4;
typedef unsigned short u16;
typedef unsigned int   u32;

// ---- bf16 <-> f32 helpers ----
__device__ __forceinline__ float b2f(u16 u) {
    union { u32 i; float f; } v; v.i = ((u32)u) << 16; return v.f;
}
__device__ __forceinline__ u16 f2b(float f) {
    union { float f; u32 i; } v; v.f = f;
    u32 r = v.i + 0x7fffu + ((v.i >> 16) & 1u);   // round-to-nearest-even
    return (u16)(r >> 16);
}
__device__ __forceinline__ float sigf(float x) {
    return __builtin_amdgcn_rcpf(1.f + __expf(-x));
}
__device__ __forceinline__ float tanhf_fast(float x) {
    float e = __expf(2.f * x);
    return 1.f - 2.f * __builtin_amdgcn_rcpf(e + 1.f);
}

// ---- dtype detector: flag=1 if float tensors are bf16, 0 if f32 ----
__global__ void k_detect(const u16* __restrict__ emb_u, int* __restrict__ flag) {
    __shared__ int cnt;
    if (threadIdx.x == 0) cnt = 0;
    __syncthreads();
    float v = b2f(emb_u[2 * threadIdx.x + 64]);
    float a = fabsf(v);
    if (a > 1e-4f && a < 16.f) atomicAdd(&cnt, 1);
    __syncthreads();
    if (threadIdx.x == 0) *flag = (cnt > 128) ? 1 : 0;
}

// ---- weight packing: gate-row permutation row' = 4*j + t (t: 0=i,1=f,2=g,3=o) ----
__global__ void k_packw(const void* __restrict__ src, u16* __restrict__ dst,
                        int Kin, int Kpad, int total, const int* __restrict__ flag) {
    int i = blockIdx.x * 256 + threadIdx.x;
    if (i >= total) return;
    int n = i / Kpad, k = i - n * Kpad;
    int d = n >> 9, r = n & 511, j = r >> 2, t = r & 3;
    size_t si = (size_t)((d << 9) + (t << 7) + j) * Kin + k;
    u16 v = 0;
    if (k < Kin) {
        if (*flag) v = ((const u16*)src)[si];
        else       v = f2b(((const float*)src)[si]);
    }
    dst[i] = v;
}

__global__ void k_packb(const void* __restrict__ src, float* __restrict__ dst,
                        const int* __restrict__ flag) {
    int i = blockIdx.x * 256 + threadIdx.x;
    if (i >= 1024) return;
    int d = i >> 9, r = i & 511, j = r >> 2, t = r & 3;
    size_t si = (d << 9) + (t << 7) + j;
    dst[i] = (*flag) ? b2f(((const u16*)src)[si]) : ((const float*)src)[si];
}

// ---- FUSED kernel: blocks [0,nlstm) = LSTM role (chunk k, r6-proven internals);
// blocks [nlstm, nlstm+ngemm) = GEMM role (chunk k+1 -> gx_out, 128x128 tiles).
// Roles are CU-exclusive: 1024 thr + 84 KiB LDS => 1 block/CU; lstm blocks
// dispatch first. gemm(k+1) has no dependency on lstm(k): L0 gemm reads
// emb/tok; L1 gemm reads h0seq (written only by the L0 phase).
template<int KPAD, bool EMBED, bool IS_L0>
__global__ __launch_bounds__(1024) void k_fused(
    const int* __restrict__ tok, const void* __restrict__ Asrc,
    const u16* __restrict__ W, const float* __restrict__ bias,
    u16* __restrict__ gx_out, const u16* __restrict__ gx_in,
    const u16* __restrict__ Whp,
    u16* __restrict__ h0seq, float* __restrict__ hT,
    u16* __restrict__ hstate, float* __restrict__ cstate,
    int k, int nlstm, int soff0g, int soff1g, const int* __restrict__ flag)
{
    __shared__ __align__(16) char smem[SMEM_BYTES];
    const int tid = threadIdx.x;

    if ((int)blockIdx.x < nlstm) {
        // ================= LSTM role (r6-proven) =================
        u16* hb = (u16*)smem;                    // [2][16][136]
        u16* gb = (u16*)(smem + 8704);           // [2][16][520]
        const int d    = blockIdx.x >> 4;
        const int bg   = blockIdx.x & 15;
        const int wv   = tid >> 6, lane = tid & 63, quad = lane >> 4, col = lane & 15;
        const int soff = (d == 0) ? CH * k : CH * (NCH - 1 - k);

        for (int i = tid; i < 2 * 16 * 136; i += 1024) hb[i] = 0;
        __syncthreads();                          // zero visible before state load
        if (k > 0) {
            for (int i = tid; i < 16 * 128; i += 1024) {
                int bl = i >> 7, j = i & 127;
                hb[bl * 136 + j] = hstate[((size_t)d * BATCH + bg * 16 + bl) * 128 + j];
            }
        }

        // A-frags of W_hh: A[m=lane&15][k=quad*8+j]  [m120-verified]
        const u16* Wd = Whp + (size_t)d * 512 * 128;
        bf16x8 wf[2][4];
#pragma unroll
        for (int mt = 0; mt < 2; ++mt)
#pragma unroll
            for (int ks = 0; ks < 4; ++ks)
                wf[mt][ks] = *(const bf16x8*)(Wd + (size_t)(((wv * 2 + mt) * 16) + col) * 128 + ks * 32 + quad * 8);

        const u16* gxd = gx_in + (size_t)d * GXC_DIR;
        auto sloc = [&](int si) { return (d == 0) ? si : (CH - 1 - si); };
        auto prefetch = [&](int si, int P) {
            const u16* g0 = gxd + ((size_t)sloc(si) * BATCH + bg * 16 + wv) * 512 + lane * 8;
            __builtin_amdgcn_global_load_lds((const __attribute__((address_space(1))) void*)g0,
                (__attribute__((address_space(3))) void*)(gb + (P * 16 + wv) * 520), 16, 0, 0);
        };

        float c[2];
#pragma unroll
        for (int mt = 0; mt < 2; ++mt)
            c[mt] = (k > 0) ? cstate[((size_t)d * BATCH + bg * 16 + col) * 128 + (wv * 2 + mt) * 4 + quad] : 0.f;

        auto step = [&](int si, int P) {
            if (si + 1 < CH) prefetch(si + 1, P ^ 1);
            if constexpr (IS_L0) {
                if (si > 0) {                     // store PREV step's h (published by barrier)
                    int sp = soff + ((d == 0) ? (si - 1) : (CH - si));
                    ushort2 hv = *(const ushort2*)(hb + (P * 16 + wv) * 136 + lane * 2);
                    *(ushort2*)(h0seq + ((size_t)sp * BATCH + bg * 16 + wv) * 256 + (d << 7) + lane * 2) = hv;
                }
            }
            bf16x8 hf[4];
#pragma unroll
            for (int ks = 0; ks < 4; ++ks)
                hf[ks] = *(const bf16x8*)(hb + (P * 16 + col) * 136 + ks * 32 + quad * 8);
            f32x4 z[2];
#pragma unroll
            for (int mt = 0; mt < 2; ++mt) {
                ushort4 gv = *(const ushort4*)(gb + (P * 16 + col) * 520 + (wv * 2 + mt) * 16 + quad * 4);
                z[mt][0] = b2f(gv.x); z[mt][1] = b2f(gv.y); z[mt][2] = b2f(gv.z); z[mt][3] = b2f(gv.w);
            }
#pragma unroll
            for (int ks = 0; ks < 4; ++ks)
#pragma unroll
                for (int mt = 0; mt < 2; ++mt)
                    z[mt] = __builtin_amdgcn_mfma_f32_16x16x32_bf16(wf[mt][ks], hf[ks], z[mt], 0, 0, 0);
#pragma unroll
            for (int mt = 0; mt < 2; ++mt) {
                float iv = sigf(z[mt][0]), fv = sigf(z[mt][1]);
                float gg = tanhf_fast(z[mt][2]), ov = sigf(z[mt][3]);
                c[mt] = fv * c[mt] + iv * gg;
                float hv = ov * tanhf_fast(c[mt]);
                const int j = (wv * 2 + mt) * 4 + quad;
                hb[((P ^ 1) * 16 + col) * 136 + j] = f2b(hv);
                if constexpr (!IS_L0) {
                    if (k == NCH - 1 && si == CH - 1)
                        hT[((size_t)d * BATCH + bg * 16 + col) * 128 + j] = hv;
                }
            }
            __syncthreads();
        };

        prefetch(0, 0);
        __syncthreads();                          // hbuf init + gx(step 0) visible

        for (int si = 0; si < CH; si += 2) {
            step(si, 0);
            step(si + 1, 1);
        }

        if constexpr (IS_L0) {                    // final step's h (in hbuf[0])
            int sp = soff + ((d == 0) ? (CH - 1) : 0);
            ushort2 hv = *(const ushort2*)(hb + wv * 136 + lane * 2);
            *(ushort2*)(h0seq + ((size_t)sp * BATCH + bg * 16 + wv) * 256 + (d << 7) + lane * 2) = hv;
        }
        if (k < NCH - 1) {                        // persist h/c for next chunk
            for (int i = tid; i < 16 * 128; i += 1024) {
                int bl = i >> 7, j = i & 127;
                hstate[((size_t)d * BATCH + bg * 16 + bl) * 128 + j] = hb[bl * 136 + j];
            }
#pragma unroll
            for (int mt = 0; mt < 2; ++mt)
                cstate[((size_t)d * BATCH + bg * 16 + col) * 128 + (wv * 2 + mt) * 4 + quad] = c[mt];
        }
        return;
    }

    // ================= GEMM role: 128x128 tile, 16 waves =================
    const int g   = (int)blockIdx.x - nlstm;
    u16* As = (u16*)smem;                         // [128][40]
    u16* Bs = (u16*)(smem + 10240);               // [128][40]
    const int gy  = g >> 8;                       // 0..7 (n-tile); m fastest for B-reuse
    const int m0  = (g & 255) * 128;              // within chunk (0..32767)
    const int dir = gy >> 2;
    const int n0  = (gy & 3) * 128;               // within dir's 512
    const int soff = dir ? soff1g : soff0g;
    const size_t mg0 = (size_t)soff * BATCH;
    const int w = tid >> 6, lane = tid & 63, quad = lane >> 4, l16 = lane & 15;
    const int wm = w >> 2, wn = w & 3;
    const int crow = (tid & 511) >> 2, cseg = tid & 3;
    const bool isA = tid < 512;

    bool is_bf = true;
    size_t arow_off = 0;
    const u16* brow = nullptr;
    if (isA) {
        if constexpr (EMBED) {
            size_t m = mg0 + m0 + crow;
            int s = (int)(m >> 8), b = (int)(m & 255);
            is_bf = (*flag != 0);
            arow_off = (size_t)tok[b * S_LEN + s] * EMB_D;
        } else {
            arow_off = (mg0 + m0 + crow) * KPAD;
        }
    } else {
        brow = W + (size_t)(dir * 512 + n0 + crow) * KPAD;
    }

    f32x4 acc[2][2] = {};
    const int KSTEPS = KPAD / 32;
#pragma unroll
    for (int kk = 0; kk < KSTEPS; ++kk) {
        uint4 v;
        if (isA) {
            if constexpr (EMBED) {
                u32 u[4];
                if (is_bf) {
                    const u16* ar = (const u16*)Asrc + arow_off;
#pragma unroll
                    for (int i = 0; i < 4; ++i) {
                        int cc = kk * 32 + cseg * 8 + 2 * i;    // even -> 4B aligned pair
                        u[i] = (cc < EMB_D) ? *(const u32*)(ar + cc) : 0u;
                    }
                } else {
                    const float* ar = (const float*)Asrc + arow_off;
#pragma unroll
                    for (int i = 0; i < 4; ++i) {
                        int cc = kk * 32 + cseg * 8 + 2 * i;
                        if (cc < EMB_D) {
                            float2 f = *(const float2*)(ar + cc);
                            u[i] = (u32)f2b(f.x) | ((u32)f2b(f.y) << 16);
                        } else u[i] = 0u;
                    }
                }
                v.x = u[0]; v.y = u[1]; v.z = u[2]; v.w = u[3];
            } else {
                v = *((const uint4*)((const u16*)Asrc + arow_off) + kk * 4 + cseg);
            }
        } else {
            v = *((const uint4*)brow + kk * 4 + cseg);
        }
        __syncthreads();
        if (isA) *(uint4*)(As + crow * 40 + cseg * 8) = v;
        else     *(uint4*)(Bs + crow * 40 + cseg * 8) = v;
        __syncthreads();
        bf16x8 af[2], bfr[2];
#pragma unroll
        for (int mt = 0; mt < 2; ++mt)
            af[mt] = *(const bf16x8*)(As + (wm * 32 + mt * 16 + l16) * 40 + quad * 8);
#pragma unroll
        for (int nt = 0; nt < 2; ++nt)
            bfr[nt] = *(const bf16x8*)(Bs + (wn * 32 + nt * 16 + l16) * 40 + quad * 8);
#pragma unroll
        for (int mt = 0; mt < 2; ++mt)
#pragma unroll
            for (int nt = 0; nt < 2; ++nt)
                acc[mt][nt] = __builtin_amdgcn_mfma_f32_16x16x32_bf16(af[mt], bfr[nt], acc[mt][nt], 0, 0, 0);
    }
    // C/D layout: col = lane&15, row = quad*4 + reg  [m89-verified]
#pragma unroll
    for (int mt = 0; mt < 2; ++mt)
#pragma unroll
        for (int nt = 0; nt < 2; ++nt)
#pragma unroll
            for (int r = 0; r < 4; ++r) {
                int mloc = m0 + wm * 32 + mt * 16 + quad * 4 + r;
                int nloc = n0 + wn * 32 + nt * 16 + l16;
                float vv = acc[mt][nt][r] + bias[dir * 512 + nloc];
                gx_out[(size_t)dir * GXC_DIR + (size_t)mloc * 512 + nloc] = f2b(vv);
            }
}

// ---- FC head (dtype-flagged weights and output) ----
__global__ void k_fc(const float* __restrict__ hT,
                     const void* __restrict__ fc1w, const void* __restrict__ fc1b,
                     const void* __restrict__ fc2w, const void* __restrict__ fc2b,
                     void* __restrict__ out, const int* __restrict__ flag) {
    int b = blockIdx.x, j = threadIdx.x;
    bool is_bf = (*flag != 0);
    __shared__ float u[128];
    float a = is_bf ? b2f(((const u16*)fc1b)[j]) : ((const float*)fc1b)[j];
    for (int k = 0; k < 256; ++k) {
        float x = hT[((size_t)(k >> 7) * BATCH + b) * 128 + (k & 127)];
        float w = is_bf ? b2f(((const u16*)fc1w)[j * 256 + k]) : ((const float*)fc1w)[j * 256 + k];
        a += x * w;
    }
    u[j] = fmaxf(a, 0.f);
    __syncthreads();
    if (j < 2) {
        float a2 = is_bf ? b2f(((const u16*)fc2b)[j]) : ((const float*)fc2b)[j];
        for (int q = 0; q < 128; ++q) {
            float w = is_bf ? b2f(((const u16*)fc2w)[j * 128 + q]) : ((const float*)fc2w)[j * 128 + q];
            a2 += u[q] * w;
        }
        if (is_bf) ((u16*)out)[b * 2 + j] = f2b(a2);
        else       ((float*)out)[b * 2 + j] = a2;
    }
}

extern "C" void kernel_launch(void* const* d_in, const int* in_sizes, int n_in,
                              void* d_out, int out_size, void* d_ws, size_t ws_size,
                              hipStream_t stream) {
    const int*  tok   = (const int*)d_in[0];
    const void* emb   = d_in[1];
    const void* w_ih0 = d_in[2];
    const void* w_hh0 = d_in[3];
    const void* b0    = d_in[4];
    const void* w_ih1 = d_in[5];
    const void* w_hh1 = d_in[6];
    const void* b1    = d_in[7];
    const void* fc1w  = d_in[8];
    const void* fc1b  = d_in[9];
    const void* fc2w  = d_in[10];
    const void* fc2b  = d_in[11];

    char* ws = (char*)d_ws;
    size_t off = 0;
    auto alloc = [&](size_t bytes) -> void* {
        void* p = ws + off; off += (bytes + 255) & ~(size_t)255; return p;
    };
    int*   flag   = (int*)alloc(256);
    u16*   Wp0    = (u16*)alloc(1024 * 320 * 2);
    u16*   Wp1    = (u16*)alloc(1024 * 256 * 2);
    u16*   Whp0   = (u16*)alloc(1024 * 128 * 2);
    u16*   Whp1   = (u16*)alloc(1024 * 128 * 2);
    float* bp0    = (float*)alloc(1024 * 4);
    float* bp1    = (float*)alloc(1024 * 4);
    float* hT     = (float*)alloc((size_t)2 * BATCH * 128 * 4);
    u16*   hstate = (u16*)alloc((size_t)2 * BATCH * 128 * 2);
    float* cstate = (float*)alloc((size_t)2 * BATCH * 128 * 4);
    u16*   h0seq  = (u16*)alloc((size_t)SB * 256 * 2);           // 64 MiB
    size_t bufb   = 2 * GXC_DIR * sizeof(u16);                   // 64 MiB (both dirs)
    u16*   gxcA   = (u16*)alloc(bufb);
    bool overlap  = ws_size >= off + bufb;                       // room for 2nd buffer?
    u16*   gxcB   = overlap ? (u16*)alloc(bufb) : gxcA;

    k_detect<<<1, 256, 0, stream>>>((const u16*)emb, flag);

    k_packw<<<(1024 * 320 + 255) / 256, 256, 0, stream>>>(w_ih0, Wp0, 300, 320, 1024 * 320, flag);
    k_packw<<<(1024 * 256 + 255) / 256, 256, 0, stream>>>(w_ih1, Wp1, 256, 256, 1024 * 256, flag);
    k_packw<<<(1024 * 128 + 255) / 256, 256, 0, stream>>>(w_hh0, Whp0, 128, 128, 1024 * 128, flag);
    k_packw<<<(1024 * 128 + 255) / 256, 256, 0, stream>>>(w_hh1, Whp1, 128, 128, 1024 * 128, flag);
    k_packb<<<4, 256, 0, stream>>>(b0, bp0, flag);
    k_packb<<<4, 256, 0, stream>>>(b1, bp1, flag);

    const int NG = 2048;   // gemm blocks per chunk: 256 m-tiles x 8 n-tiles

    if (overlap) {
        // ---- L0: gemm chunk0 standalone, then lstm(k) || gemm(k+1) ----
        k_fused<320, true, true><<<NG, 1024, 0, stream>>>(
            tok, emb, Wp0, bp0, gxcA, gxcA, Whp0, h0seq, nullptr, hstate, cstate,
            0, 0, 0, CH * (NCH - 1), flag);
        for (int k = 0; k < NCH; ++k) {
            int ng = (k < NCH - 1) ? NG : 0;
            u16* gin  = (k & 1) ? gxcB : gxcA;
            u16* gout = (k & 1) ? gxcA : gxcB;
            k_fused<320, true, true><<<32 + ng, 1024, 0, stream>>>(
                tok, emb, Wp0, bp0, gout, gin, Whp0, h0seq, nullptr, hstate, cstate,
                k, 32, CH * (k + 1), CH * (NCH - 2 - k), flag);
        }
        // ---- L1 ----
        k_fused<256, false, false><<<NG, 1024, 0, stream>>>(
            nullptr, h0seq, Wp1, bp1, gxcA, gxcA, Whp1, nullptr, hT, hstate, cstate,
            0, 0, 0, CH * (NCH - 1), flag);
        for (int k = 0; k < NCH; ++k) {
            int ng = (k < NCH - 1) ? NG : 0;
            u16* gin  = (k & 1) ? gxcB : gxcA;
            u16* gout = (k & 1) ? gxcA : gxcB;
            k_fused<256, false, false><<<32 + ng, 1024, 0, stream>>>(
                nullptr, h0seq, Wp1, bp1, gout, gin, Whp1, nullptr, hT, hstate, cstate,
                k, 32, CH * (k + 1), CH * (NCH - 2 - k), flag);
        }
    } else {
        // ---- serial fallback (r6 schedule), single gxc buffer ----
        for (int k = 0; k < NCH; ++k) {
            k_fused<320, true, true><<<NG, 1024, 0, stream>>>(
                tok, emb, Wp0, bp0, gxcA, gxcA, Whp0, h0seq, nullptr, hstate, cstate,
                0, 0, CH * k, CH * (NCH - 1 - k), flag);
            k_fused<320, true, true><<<32, 1024, 0, stream>>>(
                tok, emb, Wp0, bp0, gxcA, gxcA, Whp0, h0seq, nullptr, hstate, cstate,
                k, 32, 0, 0, flag);
        }
        for (int k = 0; k < NCH; ++k) {
            k_fused<256, false, false><<<NG, 1024, 0, stream>>>(
                nullptr, h0seq, Wp1, bp1, gxcA, gxcA, Whp1, nullptr, hT, hstate, cstate,
                0, 0, CH * k, CH * (NCH - 1 - k), flag);
            k_fused<256, false, false><<<32, 1024, 0, stream>>>(
                nullptr, h0seq, Wp1, bp1, gxcA, gxcA, Whp1, nullptr, hT, hstate, cstate,
                k, 32, 0, 0, flag);
        }
    }
    k_fc<<<256, 128, 0, stream>>>(hT, fc1w, fc1b, fc2w, fc2b, d_out, flag);
}